// Round 3
// baseline (179.923 us; speedup 1.0000x reference)
//
#include <hip/hip_runtime.h>

// Segment-mean of subtoken embeddings (sorted segment ids) -> token embeddings.
//
// Phase 1 (table_kernel): flat lower-bound table over GLOBAL token ids
//   g = b*T + t (globally sorted across the flattened [B*S] subtoken array).
//   table[g] = first flat subtoken index s with (b(s)*T + seg[s]) >= g;
//   table[BT] = B*S. Each entry written exactly once.
// Phase 2 (seg_mean_kernel<NCH>): one WAVE per 4 consecutive tokens.
//   Wave loads its 5 bounds (one cache line), then streams the contiguous
//   flat rows [table[g0], table[g0+4]) with NCH independent float4 loads
//   per lane per row (D = NCH*256 floats). No T load, no idiv, 16x fewer
//   blocks than round 2 -> whole grid co-resident, high MLP.

#define TPW 4          // tokens per wave
#define WPB 4          // waves per block (256 threads)
#define TPB (TPW * WPB)

__global__ void table_kernel(const int* __restrict__ seg,
                             const int* __restrict__ num_tokens_p,
                             int* __restrict__ table,
                             int BS_total,   // B*S
                             int BT) {       // B*T
  const int T = num_tokens_p[0];
  const int B = BT / T;
  const int S = BS_total / B;
  int s = blockIdx.x * blockDim.x + threadIdx.x;
  if (s >= BS_total) return;
  const int b = s / S;
  const int cur = b * T + seg[s];
  const int prev = (s == 0) ? -1 : ((s - 1) / S) * T + seg[s - 1];
  for (int g = prev + 1; g <= cur; ++g) table[g] = s;
  if (s == BS_total - 1) {
    for (int g = cur + 1; g <= BT; ++g) table[g] = BS_total;
  }
}

template <int NCH>
__global__ __launch_bounds__(WPB * 64) void seg_mean_kernel(
    const float* __restrict__ hs,      // [B*S, D] flat
    const int* __restrict__ table,     // [BT+1]
    float* __restrict__ out,           // [BT, D] flat
    int BT,
    int D4) {                          // D/4 (= NCH*64)
  const int lane = threadIdx.x & 63;
  const int wid = threadIdx.x >> 6;
  const int g0 = (blockIdx.x * WPB + wid) * TPW;
  if (g0 >= BT) return;
  const int n = min(TPW, BT - g0);

  int bnd[TPW + 1];
#pragma unroll
  for (int i = 0; i <= TPW; ++i) bnd[i] = (i <= n) ? table[g0 + i] : 0;

  const float4* __restrict__ hs4 = (const float4*)hs;
  float4* __restrict__ out4 = (float4*)out;

  int r = bnd[0];
  for (int tok = 0; tok < n; ++tok) {
    const int rend = bnd[tok + 1];
    float4 acc[NCH];
#pragma unroll
    for (int c = 0; c < NCH; ++c) acc[c] = make_float4(0.f, 0.f, 0.f, 0.f);
    for (; r < rend; ++r) {
      const float4* __restrict__ p = hs4 + (size_t)r * D4 + lane;
#pragma unroll
      for (int c = 0; c < NCH; ++c) {
        float4 v = p[c * 64];
        acc[c].x += v.x; acc[c].y += v.y; acc[c].z += v.z; acc[c].w += v.w;
      }
    }
    const int cnt = rend - bnd[tok];
    const float inv = (cnt > 0) ? (1.0f / (float)cnt) : 0.0f;
    float4* __restrict__ q = out4 + (size_t)(g0 + tok) * D4 + lane;
#pragma unroll
    for (int c = 0; c < NCH; ++c) {
      q[c * 64] = make_float4(acc[c].x * inv, acc[c].y * inv,
                              acc[c].z * inv, acc[c].w * inv);
    }
  }
}

// Generic fallback: one block per token, scalar loop over d. Only used if
// D is not a multiple of 256 (NCH path not applicable).
__global__ void seg_mean_fallback(const float* __restrict__ hs,
                                  const int* __restrict__ table,
                                  float* __restrict__ out,
                                  int D) {
  const int g = blockIdx.x;
  const int lo = table[g];
  const int hi = table[g + 1];
  const int cnt = hi - lo;
  const float inv = (cnt > 0) ? (1.0f / (float)cnt) : 0.0f;
  for (int d = threadIdx.x; d < D; d += blockDim.x) {
    float a = 0.f;
    for (int r = lo; r < hi; ++r) a += hs[(size_t)r * D + d];
    out[(size_t)g * D + d] = a * inv;
  }
}

extern "C" void kernel_launch(void* const* d_in, const int* in_sizes, int n_in,
                              void* d_out, int out_size, void* d_ws, size_t ws_size,
                              hipStream_t stream) {
  const float* hs = (const float*)d_in[0];
  const int* seg = (const int*)d_in[1];
  const int* num_tokens_p = (const int*)d_in[2];
  float* out = (float*)d_out;

  const int BS_total = in_sizes[1];            // B*S
  const int D = in_sizes[0] / in_sizes[1];     // 768
  const int BT = out_size / D;                 // B*T

  int* table = (int*)d_ws;                     // BT+1 ints

  const int threads1 = 256;
  const int grid1 = (BS_total + threads1 - 1) / threads1;
  hipLaunchKernelGGL(table_kernel, dim3(grid1), dim3(threads1), 0, stream,
                     seg, num_tokens_p, table, BS_total, BT);

  const int D4 = D / 4;
  const int grid2 = (BT + TPB - 1) / TPB;
  if (D % 4 == 0 && D4 % 64 == 0 && D4 / 64 >= 1 && D4 / 64 <= 4) {
    switch (D4 / 64) {
      case 1:
        hipLaunchKernelGGL(seg_mean_kernel<1>, dim3(grid2), dim3(WPB * 64), 0,
                           stream, hs, table, out, BT, D4);
        break;
      case 2:
        hipLaunchKernelGGL(seg_mean_kernel<2>, dim3(grid2), dim3(WPB * 64), 0,
                           stream, hs, table, out, BT, D4);
        break;
      case 3:
        hipLaunchKernelGGL(seg_mean_kernel<3>, dim3(grid2), dim3(WPB * 64), 0,
                           stream, hs, table, out, BT, D4);
        break;
      default:
        hipLaunchKernelGGL(seg_mean_kernel<4>, dim3(grid2), dim3(WPB * 64), 0,
                           stream, hs, table, out, BT, D4);
        break;
    }
  } else {
    hipLaunchKernelGGL(seg_mean_fallback, dim3(BT), dim3(256), 0, stream,
                       hs, table, out, D);
  }
}